// Round 2
// baseline (631.830 us; speedup 1.0000x reference)
//
#include <hip/hip_runtime.h>
#include <hip/hip_bf16.h>
#include <math.h>

typedef __bf16 bf16_t;
typedef __attribute__((ext_vector_type(8))) __bf16 bf16x8;
typedef __attribute__((ext_vector_type(4))) __bf16 bf16x4;
typedef __attribute__((ext_vector_type(4))) float f32x4;

typedef __attribute__((address_space(1))) unsigned as1u;
typedef __attribute__((address_space(3))) unsigned as3u;

__device__ __forceinline__ void async_copy16(bf16_t* lds, const bf16_t* g) {
  __builtin_amdgcn_global_load_lds((as1u*)g, (as3u*)lds, 16, 0, 0);
}

__device__ __forceinline__ float gelu_exact(float t) {
  return 0.5f * t * (1.0f + erff(t * 0.70710678118654752f));
}

// ---------------------------------------------------------------- cast f32->bf16
__global__ __launch_bounds__(256)
void cast_kernel(const float* __restrict__ w, bf16_t* __restrict__ o, int n) {
  int i = (blockIdx.x * 256 + threadIdx.x) * 4;
  if (i < n) {
    float4 v = *(const float4*)(w + i);
    bf16x4 t;
    t[0] = (bf16_t)v.x; t[1] = (bf16_t)v.y; t[2] = (bf16_t)v.z; t[3] = (bf16_t)v.w;
    *(bf16x4*)(o + i) = t;
  }
}

// ---------------------------------------------------------------- LN1 + in-mask -> bf16
__global__ __launch_bounds__(256)
void ln1_kernel(const float* __restrict__ x, const float* __restrict__ gam,
                const float* __restrict__ bet, const int* __restrict__ em,
                bf16_t* __restrict__ xn) {
  const int row = blockIdx.x, tid = threadIdx.x;
  const float4 v = ((const float4*)(x + (size_t)row * 1024))[tid];
  float s = v.x + v.y + v.z + v.w;
  float sq = v.x * v.x + v.y * v.y + v.z * v.z + v.w * v.w;
  #pragma unroll
  for (int off = 1; off < 64; off <<= 1) { s += __shfl_xor(s, off); sq += __shfl_xor(sq, off); }
  __shared__ float red[8];
  const int wave = tid >> 6, lane = tid & 63;
  if (lane == 0) { red[wave] = s; red[4 + wave] = sq; }
  __syncthreads();
  s = red[0] + red[1] + red[2] + red[3];
  sq = red[4] + red[5] + red[6] + red[7];
  const float mean = s * (1.0f / 1024.0f);
  const float var = sq * (1.0f / 1024.0f) - mean * mean;
  const float rstd = rsqrtf(var + 1e-5f);
  const int din = 1024 >> (3 - em[row]);
  const float4 gv = ((const float4*)gam)[tid];
  const float4 bv = ((const float4*)bet)[tid];
  const int c0 = tid * 4;
  float vf[4] = {v.x, v.y, v.z, v.w};
  float gf[4] = {gv.x, gv.y, gv.z, gv.w};
  float bvf[4] = {bv.x, bv.y, bv.z, bv.w};
  bf16x4 o;
  #pragma unroll
  for (int i = 0; i < 4; ++i) {
    float t = (vf[i] - mean) * rstd * gf[i] + bvf[i];
    o[i] = (c0 + i < din) ? (bf16_t)t : (bf16_t)0.0f;
  }
  *(bf16x4*)(xn + (size_t)row * 1024 + c0) = o;
}

// ---------------------------------------------------------------- LN2 over k and v, in place (bf16)
__global__ __launch_bounds__(256)
void ln2_kernel(bf16_t* __restrict__ kv, const float* __restrict__ gam,
                const float* __restrict__ bet) {
  const int row = blockIdx.x, tid = threadIdx.x;
  bf16_t* base = kv + (size_t)row * 2048;
  bf16x4 kk = *(const bf16x4*)(base + tid * 4);
  bf16x4 vv = *(const bf16x4*)(base + 1024 + tid * 4);
  float kf[4], vf[4];
  float ks = 0, ksq = 0, vs = 0, vsq = 0;
  #pragma unroll
  for (int i = 0; i < 4; ++i) {
    kf[i] = (float)kk[i]; ks += kf[i]; ksq += kf[i] * kf[i];
    vf[i] = (float)vv[i]; vs += vf[i]; vsq += vf[i] * vf[i];
  }
  #pragma unroll
  for (int off = 1; off < 64; off <<= 1) {
    ks += __shfl_xor(ks, off); ksq += __shfl_xor(ksq, off);
    vs += __shfl_xor(vs, off); vsq += __shfl_xor(vsq, off);
  }
  __shared__ float red[16];
  const int wave = tid >> 6, lane = tid & 63;
  if (lane == 0) { red[wave] = ks; red[4 + wave] = ksq; red[8 + wave] = vs; red[12 + wave] = vsq; }
  __syncthreads();
  ks = red[0] + red[1] + red[2] + red[3];
  ksq = red[4] + red[5] + red[6] + red[7];
  vs = red[8] + red[9] + red[10] + red[11];
  vsq = red[12] + red[13] + red[14] + red[15];
  const float mk = ks * (1.f / 1024.f), mv = vs * (1.f / 1024.f);
  const float rk = rsqrtf(ksq * (1.f / 1024.f) - mk * mk + 1e-5f);
  const float rv = rsqrtf(vsq * (1.f / 1024.f) - mv * mv + 1e-5f);
  const float4 gv = ((const float4*)gam)[tid];
  const float4 bv = ((const float4*)bet)[tid];
  float gf[4] = {gv.x, gv.y, gv.z, gv.w}, bvf[4] = {bv.x, bv.y, bv.z, bv.w};
  bf16x4 ko, vo;
  #pragma unroll
  for (int i = 0; i < 4; ++i) {
    ko[i] = (bf16_t)((kf[i] - mk) * rk * gf[i] + bvf[i]);
    vo[i] = (bf16_t)((vf[i] - mv) * rv * gf[i] + bvf[i]);
  }
  *(bf16x4*)(base + tid * 4) = ko;
  *(bf16x4*)(base + 1024 + tid * 4) = vo;
}

// ---------------------------------------------------------------- 256x256 8-phase GEMM (T2+T3+T4+T5)
// C[m,o] = sum_k A[m,k]*W[o,k]. BM=BN=256, BK=64, 8 waves (2M x 4N, interleaved row map),
// per-phase: 1 MFMA quadrant (16 mfma) + 1 half-tile stage; vmcnt(4) at ph4/ph8 only.
// LDS 128 KiB double-buffered; XOR slot swizzle (slot ^= row&7) on both stage-src and ds_read.

#define STG(L, G, T, H2) do { \
    async_copy16((L) + (H2)*8192 + w*512, (G) + ((size_t)((H2)*128)) * Ks + (size_t)(T)*64); \
    async_copy16((L) + (H2)*8192 + 4096 + w*512, (G) + ((size_t)((H2)*128 + 64)) * Ks + (size_t)(T)*64); \
  } while (0)

#define PHASE(BUF, H, G_, LOADB, STG_STMT, VMW) do { \
    bf16x8 afr[4][2]; \
    _Pragma("unroll") \
    for (int mi = 0; mi < 4; ++mi) { \
      const int rA = (H)*128 + WM*64 + mi*16 + l15; \
      afr[mi][0] = *(const bf16x8*)(&As[BUF][rA*64 + ((l4 ^ sw) & 7)*8]); \
      afr[mi][1] = *(const bf16x8*)(&As[BUF][rA*64 + (((4 + l4) ^ sw) & 7)*8]); \
    } \
    if (LOADB) { \
      _Pragma("unroll") \
      for (int ni = 0; ni < 2; ++ni) { \
        const int rB = (G_)*128 + WN*32 + ni*16 + l15; \
        bfr[ni][0] = *(const bf16x8*)(&Bs[BUF][rB*64 + ((l4 ^ sw) & 7)*8]); \
        bfr[ni][1] = *(const bf16x8*)(&Bs[BUF][rB*64 + (((4 + l4) ^ sw) & 7)*8]); \
      } \
    } \
    STG_STMT; \
    __builtin_amdgcn_s_barrier(); \
    asm volatile("s_waitcnt lgkmcnt(0)" ::: "memory"); \
    __builtin_amdgcn_s_setprio(1); \
    _Pragma("unroll") \
    for (int mi = 0; mi < 4; ++mi) { \
      _Pragma("unroll") \
      for (int ni = 0; ni < 2; ++ni) { \
        acc[H][G_][mi][ni] = __builtin_amdgcn_mfma_f32_16x16x32_bf16(afr[mi][0], bfr[ni][0], acc[H][G_][mi][ni], 0, 0, 0); \
        acc[H][G_][mi][ni] = __builtin_amdgcn_mfma_f32_16x16x32_bf16(afr[mi][1], bfr[ni][1], acc[H][G_][mi][ni], 0, 0, 0); \
      } \
    } \
    __builtin_amdgcn_s_setprio(0); \
    VMW; \
    __builtin_amdgcn_s_barrier(); \
  } while (0)

template<int EPI>
__global__ __launch_bounds__(512, 2)
void gemm8(const bf16_t* __restrict__ A, const bf16_t* __restrict__ Wt, const int K,
           const float* __restrict__ bias,
           bf16_t* __restrict__ q_bf, bf16_t* __restrict__ kv_bf, bf16_t* __restrict__ h_bf,
           float* __restrict__ Z) {
  __shared__ bf16_t As[2][16384];
  __shared__ bf16_t Bs[2][16384];
  const int tid = threadIdx.x;
  const int w = tid >> 6, l = tid & 63;
  const int l15 = l & 15, l4 = l >> 4;
  const int lr = l >> 3, ls = l & 7;
  const int gs = ls ^ lr;          // inverse-swizzled source slot
  const int sw = l15 & 7;          // read-side swizzle key (row & 7)
  const int WM = w >> 2, WN = w & 3;

  // bijective XCD swizzle (gridDim.x % 8 == 0 for both GEMMs)
  int wg = blockIdx.x;
  const int cpx = gridDim.x >> 3;
  wg = (wg & 7) * cpx + (wg >> 3);
  const int bm = wg & 31;          // nbm = 32 (M = 8192), fastest -> B-panel L2 reuse
  const int bn = wg >> 5;

  const size_t Ks = (size_t)K;
  const bf16_t* Ag0 = A + (size_t)(bm * 256 + w * 8 + lr) * Ks + gs * 8;
  const bf16_t* Wg0 = Wt + (size_t)(bn * 256 + w * 8 + lr) * Ks + gs * 8;

  f32x4 acc[2][2][4][2] = {};
  bf16x8 bfr[2][2];

  const int ktiles = K >> 6;
  const int iters = ktiles >> 1;

  // prologue: 6 half-tiles (t0 complete, t1.B0, t1.A0)
  STG(As[0], Ag0, 0, 0);
  STG(Bs[0], Wg0, 0, 0);
  STG(As[0], Ag0, 0, 1);
  STG(Bs[0], Wg0, 0, 1);
  STG(Bs[1], Wg0, 1, 0);
  STG(As[1], Ag0, 1, 0);
  asm volatile("s_waitcnt vmcnt(4)" ::: "memory");
  __builtin_amdgcn_s_barrier();

  for (int it = 0; it < iters; ++it) {
    const int s1 = 2 * it + 1;
    int s2 = 2 * it + 2; if (s2 >= ktiles) s2 -= ktiles;  // wrap: harmless in-bounds prefetch
    int s3 = 2 * it + 3; if (s3 >= ktiles) s3 -= ktiles;
    PHASE(0, 0, 0, 1, STG(As[1], Ag0, s1, 1), ((void)0));                                   // ph1
    PHASE(0, 1, 0, 0, STG(Bs[1], Wg0, s1, 1), ((void)0));                                   // ph2
    PHASE(0, 0, 1, 1, STG(Bs[0], Wg0, s2, 0), ((void)0));                                   // ph3
    PHASE(0, 1, 1, 0, STG(As[0], Ag0, s2, 0), asm volatile("s_waitcnt vmcnt(4)" ::: "memory")); // ph4
    PHASE(1, 0, 0, 1, STG(As[0], Ag0, s2, 1), ((void)0));                                   // ph5
    PHASE(1, 1, 0, 0, STG(Bs[0], Wg0, s2, 1), ((void)0));                                   // ph6
    PHASE(1, 0, 1, 1, STG(Bs[1], Wg0, s3, 0), ((void)0));                                   // ph7
    PHASE(1, 1, 1, 0, STG(As[1], Ag0, s3, 0), asm volatile("s_waitcnt vmcnt(4)" ::: "memory")); // ph8
  }

  // epilogue; C/D layout: row = l4*4 + r, col = l15
  #pragma unroll
  for (int h = 0; h < 2; ++h) {
    #pragma unroll
    for (int g = 0; g < 2; ++g) {
      #pragma unroll
      for (int mi = 0; mi < 4; ++mi) {
        #pragma unroll
        for (int ni = 0; ni < 2; ++ni) {
          const int gc = bn * 256 + g * 128 + WN * 32 + ni * 16 + l15;
          #pragma unroll
          for (int r = 0; r < 4; ++r) {
            const int gm = bm * 256 + h * 128 + WM * 64 + mi * 16 + l4 * 4 + r;
            const float c = acc[h][g][mi][ni][r];
            if (EPI == 0) {
              if (gc < 1024) {
                q_bf[(size_t)gm * 1024 + gc] = (bf16_t)c;
              } else if (gc < 3072) {
                kv_bf[(size_t)gm * 2048 + (gc - 1024)] = (bf16_t)c;
              } else {
                const float t = c + bias[gc - 3072];
                h_bf[(size_t)gm * 5120 + 1024 + (gc - 3072)] = (bf16_t)gelu_exact(t);
              }
            } else {
              Z[(size_t)gm * 2048 + gc] = c + bias[gc];
            }
          }
        }
      }
    }
  }
}

// ---------------------------------------------------------------- flash attention
__global__ __launch_bounds__(256)
void attn_kernel(const bf16_t* __restrict__ qb, const bf16_t* __restrict__ kv,
                 bf16_t* __restrict__ hb) {
  __shared__ bf16_t Kl[64 * 64];
  __shared__ bf16_t Vt[64 * 72];
  __shared__ bf16_t Pl[4][16 * 72];
  const int tid = threadIdx.x;
  const int wave = tid >> 6, lane = tid & 63;
  const int l15 = lane & 15, l4 = lane >> 4;
  const int qt = blockIdx.x, bh = blockIdx.y;
  const int bb = bh >> 4, head = bh & 15;
  const int tok0 = bb << 10;
  const int d0 = head << 6;

  const int qrow = tok0 + qt * 64 + wave * 16 + l15;
  const bf16x8 aq0 = *(const bf16x8*)(qb + (size_t)qrow * 1024 + d0 + l4 * 8);
  const bf16x8 aq1 = *(const bf16x8*)(qb + (size_t)qrow * 1024 + d0 + 32 + l4 * 8);

  f32x4 o[4] = {};
  float mrun[4] = {-1e30f, -1e30f, -1e30f, -1e30f};
  float lrun[4] = {0.f, 0.f, 0.f, 0.f};

  const int krb = tid >> 3;
  const int kss = (tid & 7) ^ (krb & 7);

  for (int kt = 0; kt < 16; ++kt) {
    const int krow0 = tok0 + kt * 64;
    #pragma unroll
    for (int i = 0; i < 2; ++i) {
      const int r = i * 32 + krb;
      async_copy16(Kl + (i * 256 + wave * 64) * 8,
                   kv + (size_t)(krow0 + r) * 2048 + d0 + kss * 8);
    }
    #pragma unroll
    for (int i = 0; i < 2; ++i) {
      const int key = i * 32 + (tid >> 3);
      const int dc = tid & 7;
      bf16x8 vvv = *(const bf16x8*)(kv + (size_t)(krow0 + key) * 2048 + 1024 + d0 + dc * 8);
      #pragma unroll
      for (int j = 0; j < 8; ++j) Vt[(dc * 8 + j) * 72 + key] = vvv[j];
    }
    __syncthreads();

    f32x4 s[4] = {};
    #pragma unroll
    for (int ks = 0; ks < 2; ++ks) {
      const bf16x8 aqk = ks ? aq1 : aq0;
      #pragma unroll
      for (int kc = 0; kc < 4; ++kc) {
        const int r = kc * 16 + l15;
        const int slot = (ks * 4 + l4) ^ (r & 7);
        bf16x8 bk = *(const bf16x8*)(Kl + r * 64 + slot * 8);
        s[kc] = __builtin_amdgcn_mfma_f32_16x16x32_bf16(aqk, bk, s[kc], 0, 0, 0);
      }
    }
    #pragma unroll
    for (int r = 0; r < 4; ++r) {
      float mx = -1e30f;
      #pragma unroll
      for (int kc = 0; kc < 4; ++kc) mx = fmaxf(mx, s[kc][r]);
      mx = fmaxf(mx, __shfl_xor(mx, 1));
      mx = fmaxf(mx, __shfl_xor(mx, 2));
      mx = fmaxf(mx, __shfl_xor(mx, 4));
      mx = fmaxf(mx, __shfl_xor(mx, 8));
      mx *= 0.125f;
      const float mnew = fmaxf(mrun[r], mx);
      const float corr = __expf(mrun[r] - mnew);
      float ps = 0.f;
      #pragma unroll
      for (int kc = 0; kc < 4; ++kc) {
        const float p = __expf(s[kc][r] * 0.125f - mnew);
        ps += p;
        Pl[wave][(l4 * 4 + r) * 72 + kc * 16 + l15] = (bf16_t)p;
      }
      ps += __shfl_xor(ps, 1); ps += __shfl_xor(ps, 2);
      ps += __shfl_xor(ps, 4); ps += __shfl_xor(ps, 8);
      lrun[r] = lrun[r] * corr + ps;
      mrun[r] = mnew;
      o[0][r] *= corr; o[1][r] *= corr; o[2][r] *= corr; o[3][r] *= corr;
    }
    const bf16x8 ap0 = *(const bf16x8*)(&Pl[wave][l15 * 72 + l4 * 8]);
    const bf16x8 ap1 = *(const bf16x8*)(&Pl[wave][l15 * 72 + 32 + l4 * 8]);
    #pragma unroll
    for (int dn = 0; dn < 4; ++dn) {
      const int r = dn * 16 + l15;
      bf16x8 bv0 = *(const bf16x8*)(Vt + r * 72 + l4 * 8);
      bf16x8 bv1 = *(const bf16x8*)(Vt + r * 72 + 32 + l4 * 8);
      o[dn] = __builtin_amdgcn_mfma_f32_16x16x32_bf16(ap0, bv0, o[dn], 0, 0, 0);
      o[dn] = __builtin_amdgcn_mfma_f32_16x16x32_bf16(ap1, bv1, o[dn], 0, 0, 0);
    }
    __syncthreads();
  }

  #pragma unroll
  for (int r = 0; r < 4; ++r) {
    const float inv = 1.0f / lrun[r];
    const int gq = tok0 + qt * 64 + wave * 16 + l4 * 4 + r;
    #pragma unroll
    for (int dn = 0; dn < 4; ++dn)
      hb[(size_t)gq * 5120 + d0 + dn * 16 + l15] = (bf16_t)(o[dn][r] * inv);
  }
}

// ---------------------------------------------------------------- final combine + tuple outputs
__global__ __launch_bounds__(256)
void final_kernel(const float* __restrict__ z, const float* __restrict__ x,
                  const int* __restrict__ em, const float* __restrict__ rp,
                  const float* __restrict__ alpha, float* __restrict__ out) {
  const int row = blockIdx.x, tid = threadIdx.x;
  const int e = em[row];
  const int dout = 2048 >> (3 - e);
  const float f = alpha[0] * rp[row * 4 + e] + 1.0f;
  const float* zr = z + (size_t)row * 2048;
  const float4 z0 = ((const float4*)zr)[tid];
  const float4 z1 = ((const float4*)(zr + 1024))[tid];
  const float4 xv = ((const float4*)(x + (size_t)row * 1024))[tid];
  const int c = tid * 4;
  float4 o;
  o.x = ((c + 0) < dout ? z0.x : 0.f) + xv.x + f * ((1024 + c + 0) < dout ? z1.x : 0.f);
  o.y = ((c + 1) < dout ? z0.y : 0.f) + xv.y + f * ((1024 + c + 1) < dout ? z1.y : 0.f);
  o.z = ((c + 2) < dout ? z0.z : 0.f) + xv.z + f * ((1024 + c + 2) < dout ? z1.z : 0.f);
  o.w = ((c + 3) < dout ? z0.w : 0.f) + xv.w + f * ((1024 + c + 3) < dout ? z1.w : 0.f);
  ((float4*)(out + (size_t)row * 1024))[tid] = o;
  float* out_em = out + 8388608;
  float* out_rp = out_em + 8192;
  if (tid == 0) out_em[row] = (float)e;
  if (tid < 4) out_rp[row * 4 + tid] = rp[row * 4 + tid];
}

// ---------------------------------------------------------------- launch
extern "C" void kernel_launch(void* const* d_in, const int* in_sizes, int n_in,
                              void* d_out, int out_size, void* d_ws, size_t ws_size,
                              hipStream_t stream) {
  const float* x = (const float*)d_in[0];
  const int* em = (const int*)d_in[1];
  const float* rp = (const float*)d_in[2];
  const float* w_exp = (const float*)d_in[3];
  const float* mlp_bias = (const float*)d_in[4];
  const float* w_con = (const float*)d_in[5];
  const float* c_bias = (const float*)d_in[6];
  const float* n1g = (const float*)d_in[7];
  const float* n1b = (const float*)d_in[8];
  const float* n2g = (const float*)d_in[9];
  const float* n2b = (const float*)d_in[10];
  const float* alpha = (const float*)d_in[11];

  char* ws = (char*)d_ws;
  bf16_t* Wexp = (bf16_t*)ws;
  bf16_t* xn   = (bf16_t*)(ws + 14680064);
  bf16_t* qb   = (bf16_t*)(ws + 14680064 + 16777216);
  bf16_t* kvb  = (bf16_t*)(ws + 14680064 + 33554432);
  bf16_t* Wcon = (bf16_t*)(ws + 14680064 + 67108864);
  bf16_t* hb   = (bf16_t*)(ws + 14680064 + 67108864 + 20971520);
  float*  z    = (float*)(ws + 14680064);  // alias over [xn|q|kv]

  cast_kernel<<<7168, 256, 0, stream>>>(w_exp, Wexp, 7340032);
  cast_kernel<<<10240, 256, 0, stream>>>(w_con, Wcon, 10485760);
  ln1_kernel<<<8192, 256, 0, stream>>>(x, n1g, n1b, em, xn);
  gemm8<0><<<32 * 28, 512, 0, stream>>>(xn, Wexp, 1024, mlp_bias, qb, kvb, hb, nullptr);
  ln2_kernel<<<8192, 256, 0, stream>>>(kvb, n2g, n2b);
  attn_kernel<<<dim3(16, 128), 256, 0, stream>>>(qb, kvb, hb);
  gemm8<1><<<32 * 8, 512, 0, stream>>>(hb, Wcon, 5120, c_bias, nullptr, nullptr, nullptr, z);
  final_kernel<<<8192, 256, 0, stream>>>(z, x, em, rp, alpha, (float*)d_out);
}

// Round 3
// 620.671 us; speedup vs baseline: 1.0180x; 1.0180x over previous
//
#include <hip/hip_runtime.h>
#include <hip/hip_bf16.h>
#include <math.h>

typedef __bf16 bf16_t;
typedef __attribute__((ext_vector_type(8))) __bf16 bf16x8;
typedef __attribute__((ext_vector_type(4))) __bf16 bf16x4;
typedef __attribute__((ext_vector_type(4))) float f32x4;

typedef __attribute__((address_space(1))) unsigned as1u;
typedef __attribute__((address_space(3))) unsigned as3u;

__device__ __forceinline__ void async_copy16(bf16_t* lds, const bf16_t* g) {
  __builtin_amdgcn_global_load_lds((as1u*)g, (as3u*)lds, 16, 0, 0);
}

__device__ __forceinline__ float gelu_exact(float t) {
  return 0.5f * t * (1.0f + erff(t * 0.70710678118654752f));
}

// ---------------------------------------------------------------- cast f32->bf16
__global__ __launch_bounds__(256)
void cast_kernel(const float* __restrict__ w, bf16_t* __restrict__ o, int n) {
  int i = (blockIdx.x * 256 + threadIdx.x) * 4;
  if (i < n) {
    float4 v = *(const float4*)(w + i);
    bf16x4 t;
    t[0] = (bf16_t)v.x; t[1] = (bf16_t)v.y; t[2] = (bf16_t)v.z; t[3] = (bf16_t)v.w;
    *(bf16x4*)(o + i) = t;
  }
}

// ---------------------------------------------------------------- LN1 + in-mask -> bf16
__global__ __launch_bounds__(256)
void ln1_kernel(const float* __restrict__ x, const float* __restrict__ gam,
                const float* __restrict__ bet, const int* __restrict__ em,
                bf16_t* __restrict__ xn) {
  const int row = blockIdx.x, tid = threadIdx.x;
  const float4 v = ((const float4*)(x + (size_t)row * 1024))[tid];
  float s = v.x + v.y + v.z + v.w;
  float sq = v.x * v.x + v.y * v.y + v.z * v.z + v.w * v.w;
  #pragma unroll
  for (int off = 1; off < 64; off <<= 1) { s += __shfl_xor(s, off); sq += __shfl_xor(sq, off); }
  __shared__ float red[8];
  const int wave = tid >> 6, lane = tid & 63;
  if (lane == 0) { red[wave] = s; red[4 + wave] = sq; }
  __syncthreads();
  s = red[0] + red[1] + red[2] + red[3];
  sq = red[4] + red[5] + red[6] + red[7];
  const float mean = s * (1.0f / 1024.0f);
  const float var = sq * (1.0f / 1024.0f) - mean * mean;
  const float rstd = rsqrtf(var + 1e-5f);
  const int din = 1024 >> (3 - em[row]);
  const float4 gv = ((const float4*)gam)[tid];
  const float4 bv = ((const float4*)bet)[tid];
  const int c0 = tid * 4;
  float vf[4] = {v.x, v.y, v.z, v.w};
  float gf[4] = {gv.x, gv.y, gv.z, gv.w};
  float bvf[4] = {bv.x, bv.y, bv.z, bv.w};
  bf16x4 o;
  #pragma unroll
  for (int i = 0; i < 4; ++i) {
    float t = (vf[i] - mean) * rstd * gf[i] + bvf[i];
    o[i] = (c0 + i < din) ? (bf16_t)t : (bf16_t)0.0f;
  }
  *(bf16x4*)(xn + (size_t)row * 1024 + c0) = o;
}

// ---------------------------------------------------------------- LN2 over k and v, in place (bf16)
__global__ __launch_bounds__(256)
void ln2_kernel(bf16_t* __restrict__ kv, const float* __restrict__ gam,
                const float* __restrict__ bet) {
  const int row = blockIdx.x, tid = threadIdx.x;
  bf16_t* base = kv + (size_t)row * 2048;
  bf16x4 kk = *(const bf16x4*)(base + tid * 4);
  bf16x4 vv = *(const bf16x4*)(base + 1024 + tid * 4);
  float kf[4], vf[4];
  float ks = 0, ksq = 0, vs = 0, vsq = 0;
  #pragma unroll
  for (int i = 0; i < 4; ++i) {
    kf[i] = (float)kk[i]; ks += kf[i]; ksq += kf[i] * kf[i];
    vf[i] = (float)vv[i]; vs += vf[i]; vsq += vf[i] * vf[i];
  }
  #pragma unroll
  for (int off = 1; off < 64; off <<= 1) {
    ks += __shfl_xor(ks, off); ksq += __shfl_xor(ksq, off);
    vs += __shfl_xor(vs, off); vsq += __shfl_xor(vsq, off);
  }
  __shared__ float red[16];
  const int wave = tid >> 6, lane = tid & 63;
  if (lane == 0) { red[wave] = ks; red[4 + wave] = ksq; red[8 + wave] = vs; red[12 + wave] = vsq; }
  __syncthreads();
  ks = red[0] + red[1] + red[2] + red[3];
  ksq = red[4] + red[5] + red[6] + red[7];
  vs = red[8] + red[9] + red[10] + red[11];
  vsq = red[12] + red[13] + red[14] + red[15];
  const float mk = ks * (1.f / 1024.f), mv = vs * (1.f / 1024.f);
  const float rk = rsqrtf(ksq * (1.f / 1024.f) - mk * mk + 1e-5f);
  const float rv = rsqrtf(vsq * (1.f / 1024.f) - mv * mv + 1e-5f);
  const float4 gv = ((const float4*)gam)[tid];
  const float4 bv = ((const float4*)bet)[tid];
  float gf[4] = {gv.x, gv.y, gv.z, gv.w}, bvf[4] = {bv.x, bv.y, bv.z, bv.w};
  bf16x4 ko, vo;
  #pragma unroll
  for (int i = 0; i < 4; ++i) {
    ko[i] = (bf16_t)((kf[i] - mk) * rk * gf[i] + bvf[i]);
    vo[i] = (bf16_t)((vf[i] - mv) * rv * gf[i] + bvf[i]);
  }
  *(bf16x4*)(base + tid * 4) = ko;
  *(bf16x4*)(base + 1024 + tid * 4) = vo;
}

// ---------------------------------------------------------------- 256x256 8-phase GEMM
// Snake quadrant order: ph1 (A0,B0)->H0G0, ph2 (A1)->H1G0, ph3 (B1)->H1G1, ph4 ()->H0G1.
// 24 ds_read_b128 / K-tile / wave. Stage 1 half-tile/phase, regions staged the phase after
// they're freed; vmcnt(6) at ph4/ph8 only (3 half-tiles always in flight).

#define STG(L, G, T, H2) do { \
    async_copy16((L) + (H2)*8192 + w*512, (G) + ((size_t)((H2)*128)) * Ks + (size_t)(T)*64); \
    async_copy16((L) + (H2)*8192 + 4096 + w*512, (G) + ((size_t)((H2)*128 + 64)) * Ks + (size_t)(T)*64); \
  } while (0)

#define RDA(DST, BUF, H) do { _Pragma("unroll") \
    for (int mi = 0; mi < 4; ++mi) { \
      const int rA = (H)*128 + WM*64 + mi*16 + l15; \
      DST[mi][0] = *(const bf16x8*)(&As[BUF][rA*64 + ((l4 ^ sw))*8]); \
      DST[mi][1] = *(const bf16x8*)(&As[BUF][rA*64 + (((4+l4) ^ sw))*8]); \
    } } while (0)

#define RDB(DST, BUF, G) do { _Pragma("unroll") \
    for (int ni = 0; ni < 2; ++ni) { \
      const int rB = (G)*128 + WN*32 + ni*16 + l15; \
      DST[ni][0] = *(const bf16x8*)(&Bs[BUF][rB*64 + ((l4 ^ sw))*8]); \
      DST[ni][1] = *(const bf16x8*)(&Bs[BUF][rB*64 + (((4+l4) ^ sw))*8]); \
    } } while (0)

#define MM(H, G, AF, BF) do { _Pragma("unroll") \
    for (int mi = 0; mi < 4; ++mi) { _Pragma("unroll") \
      for (int ni = 0; ni < 2; ++ni) { \
        acc[H][G][mi][ni] = __builtin_amdgcn_mfma_f32_16x16x32_bf16(AF[mi][0], BF[ni][0], acc[H][G][mi][ni], 0, 0, 0); \
        acc[H][G][mi][ni] = __builtin_amdgcn_mfma_f32_16x16x32_bf16(AF[mi][1], BF[ni][1], acc[H][G][mi][ni], 0, 0, 0); \
      } } } while (0)

#define VM6 asm volatile("s_waitcnt vmcnt(6)" ::: "memory")

#define PH(RDS, STGS, H, G, AF, BF, VMW) do { \
    RDS; STGS; \
    __builtin_amdgcn_s_barrier(); \
    asm volatile("s_waitcnt lgkmcnt(0)" ::: "memory"); \
    __builtin_amdgcn_sched_barrier(0); \
    __builtin_amdgcn_s_setprio(1); \
    MM(H, G, AF, BF); \
    __builtin_amdgcn_s_setprio(0); \
    VMW; \
    __builtin_amdgcn_s_barrier(); \
  } while (0)

template<int EPI>
__global__ __launch_bounds__(512, 2)
void gemm8(const bf16_t* __restrict__ A, const bf16_t* __restrict__ Wt, const int K,
           const float* __restrict__ bias,
           bf16_t* __restrict__ q_bf, bf16_t* __restrict__ kv_bf, bf16_t* __restrict__ h_bf,
           float* __restrict__ Z) {
  __shared__ bf16_t As[2][16384];
  __shared__ bf16_t Bs[2][16384];
  const int tid = threadIdx.x;
  const int w = tid >> 6, l = tid & 63;
  const int l15 = l & 15, l4 = l >> 4;
  const int lr = l >> 3, ls = l & 7;
  const int gs = ls ^ lr;          // inverse-swizzled source slot
  const int sw = l15 & 7;          // read-side swizzle key (row & 7)
  const int WM = w >> 2, WN = w & 3;

  // bijective XCD swizzle (gridDim.x % 8 == 0 for both GEMMs)
  int wg = blockIdx.x;
  const int cpx = gridDim.x >> 3;
  wg = (wg & 7) * cpx + (wg >> 3);
  const int bm = wg & 31;          // bm fastest: concurrent blocks on an XCD share the B panel
  const int bn = wg >> 5;

  const size_t Ks = (size_t)K;
  const bf16_t* Ag0 = A + (size_t)(bm * 256 + w * 8 + lr) * Ks + gs * 8;
  const bf16_t* Wg0 = Wt + (size_t)(bn * 256 + w * 8 + lr) * Ks + gs * 8;

  f32x4 acc[2][2][4][2] = {};
  bf16x8 a0[4][2], a1[4][2], b0[2][2], b1[2][2];

  const int ktiles = K >> 6;
  const int iters = ktiles >> 1;

  // prologue: tile0 complete into buf0, tile1 {A0,B0,A1} into buf1 (B1 staged at ph1)
  STG(As[0], Ag0, 0, 0);
  STG(Bs[0], Wg0, 0, 0);
  STG(As[0], Ag0, 0, 1);
  STG(Bs[0], Wg0, 0, 1);
  STG(As[1], Ag0, 1, 0);
  STG(Bs[1], Wg0, 1, 0);
  STG(As[1], Ag0, 1, 1);
  VM6;  // tile0's 8 ops complete; tile1's 6 in flight
  __builtin_amdgcn_s_barrier();

  for (int it = 0; it < iters; ++it) {
    const int t1 = 2 * it + 1;
    int u = 2 * it + 2; if (u >= ktiles) u -= ktiles;  // wrap: harmless in-bounds prefetch
    int v = 2 * it + 3; if (v >= ktiles) v -= ktiles;
    PH(RDA(a0, 0, 0); RDB(b0, 0, 0), STG(Bs[1], Wg0, t1, 1), 0, 0, a0, b0, ((void)0)); // ph1
    PH(RDA(a1, 0, 1),                STG(As[0], Ag0, u, 0),  1, 0, a1, b0, ((void)0)); // ph2
    PH(RDB(b1, 0, 1),                STG(Bs[0], Wg0, u, 0),  1, 1, a1, b1, ((void)0)); // ph3
    PH(((void)0),                    STG(As[0], Ag0, u, 1),  0, 1, a0, b1, VM6);       // ph4
    PH(RDA(a0, 1, 0); RDB(b0, 1, 0), STG(Bs[0], Wg0, u, 1),  0, 0, a0, b0, ((void)0)); // ph5
    PH(RDA(a1, 1, 1),                STG(As[1], Ag0, v, 0),  1, 0, a1, b0, ((void)0)); // ph6
    PH(RDB(b1, 1, 1),                STG(Bs[1], Wg0, v, 0),  1, 1, a1, b1, ((void)0)); // ph7
    PH(((void)0),                    STG(As[1], Ag0, v, 1),  0, 1, a0, b1, VM6);       // ph8
  }

  // epilogue; C/D layout: row = l4*4 + r, col = l15
  #pragma unroll
  for (int h = 0; h < 2; ++h) {
    #pragma unroll
    for (int g = 0; g < 2; ++g) {
      #pragma unroll
      for (int mi = 0; mi < 4; ++mi) {
        #pragma unroll
        for (int ni = 0; ni < 2; ++ni) {
          const int gc = bn * 256 + g * 128 + WN * 32 + ni * 16 + l15;
          #pragma unroll
          for (int r = 0; r < 4; ++r) {
            const int gm = bm * 256 + h * 128 + WM * 64 + mi * 16 + l4 * 4 + r;
            const float c = acc[h][g][mi][ni][r];
            if (EPI == 0) {
              if (gc < 1024) {
                q_bf[(size_t)gm * 1024 + gc] = (bf16_t)c;
              } else if (gc < 3072) {
                kv_bf[(size_t)gm * 2048 + (gc - 1024)] = (bf16_t)c;
              } else {
                const float t = c + bias[gc - 3072];
                h_bf[(size_t)gm * 5120 + 1024 + (gc - 3072)] = (bf16_t)gelu_exact(t);
              }
            } else {
              Z[(size_t)gm * 2048 + gc] = c + bias[gc];
            }
          }
        }
      }
    }
  }
}

// ---------------------------------------------------------------- flash attention
__global__ __launch_bounds__(256)
void attn_kernel(const bf16_t* __restrict__ qb, const bf16_t* __restrict__ kv,
                 bf16_t* __restrict__ hb) {
  __shared__ bf16_t Kl[64 * 64];
  __shared__ bf16_t Vt[64 * 72];
  __shared__ bf16_t Pl[4][16 * 72];
  const int tid = threadIdx.x;
  const int wave = tid >> 6, lane = tid & 63;
  const int l15 = lane & 15, l4 = lane >> 4;
  const int qt = blockIdx.x, bh = blockIdx.y;
  const int bb = bh >> 4, head = bh & 15;
  const int tok0 = bb << 10;
  const int d0 = head << 6;

  const int qrow = tok0 + qt * 64 + wave * 16 + l15;
  const bf16x8 aq0 = *(const bf16x8*)(qb + (size_t)qrow * 1024 + d0 + l4 * 8);
  const bf16x8 aq1 = *(const bf16x8*)(qb + (size_t)qrow * 1024 + d0 + 32 + l4 * 8);

  f32x4 o[4] = {};
  float mrun[4] = {-1e30f, -1e30f, -1e30f, -1e30f};
  float lrun[4] = {0.f, 0.f, 0.f, 0.f};

  const int krb = tid >> 3;
  const int kss = (tid & 7) ^ (krb & 7);

  for (int kt = 0; kt < 16; ++kt) {
    const int krow0 = tok0 + kt * 64;
    #pragma unroll
    for (int i = 0; i < 2; ++i) {
      const int r = i * 32 + krb;
      async_copy16(Kl + (i * 256 + wave * 64) * 8,
                   kv + (size_t)(krow0 + r) * 2048 + d0 + kss * 8);
    }
    #pragma unroll
    for (int i = 0; i < 2; ++i) {
      const int key = i * 32 + (tid >> 3);
      const int dc = tid & 7;
      bf16x8 vvv = *(const bf16x8*)(kv + (size_t)(krow0 + key) * 2048 + 1024 + d0 + dc * 8);
      #pragma unroll
      for (int j = 0; j < 8; ++j) Vt[(dc * 8 + j) * 72 + key] = vvv[j];
    }
    __syncthreads();

    f32x4 s[4] = {};
    #pragma unroll
    for (int ks = 0; ks < 2; ++ks) {
      const bf16x8 aqk = ks ? aq1 : aq0;
      #pragma unroll
      for (int kc = 0; kc < 4; ++kc) {
        const int r = kc * 16 + l15;
        const int slot = (ks * 4 + l4) ^ (r & 7);
        bf16x8 bk = *(const bf16x8*)(Kl + r * 64 + slot * 8);
        s[kc] = __builtin_amdgcn_mfma_f32_16x16x32_bf16(aqk, bk, s[kc], 0, 0, 0);
      }
    }
    #pragma unroll
    for (int r = 0; r < 4; ++r) {
      float mx = -1e30f;
      #pragma unroll
      for (int kc = 0; kc < 4; ++kc) mx = fmaxf(mx, s[kc][r]);
      mx = fmaxf(mx, __shfl_xor(mx, 1));
      mx = fmaxf(mx, __shfl_xor(mx, 2));
      mx = fmaxf(mx, __shfl_xor(mx, 4));
      mx = fmaxf(mx, __shfl_xor(mx, 8));
      mx *= 0.125f;
      const float mnew = fmaxf(mrun[r], mx);
      const float corr = __expf(mrun[r] - mnew);
      float ps = 0.f;
      #pragma unroll
      for (int kc = 0; kc < 4; ++kc) {
        const float p = __expf(s[kc][r] * 0.125f - mnew);
        ps += p;
        Pl[wave][(l4 * 4 + r) * 72 + kc * 16 + l15] = (bf16_t)p;
      }
      ps += __shfl_xor(ps, 1); ps += __shfl_xor(ps, 2);
      ps += __shfl_xor(ps, 4); ps += __shfl_xor(ps, 8);
      lrun[r] = lrun[r] * corr + ps;
      mrun[r] = mnew;
      o[0][r] *= corr; o[1][r] *= corr; o[2][r] *= corr; o[3][r] *= corr;
    }
    const bf16x8 ap0 = *(const bf16x8*)(&Pl[wave][l15 * 72 + l4 * 8]);
    const bf16x8 ap1 = *(const bf16x8*)(&Pl[wave][l15 * 72 + 32 + l4 * 8]);
    #pragma unroll
    for (int dn = 0; dn < 4; ++dn) {
      const int r = dn * 16 + l15;
      bf16x8 bv0 = *(const bf16x8*)(Vt + r * 72 + l4 * 8);
      bf16x8 bv1 = *(const bf16x8*)(Vt + r * 72 + 32 + l4 * 8);
      o[dn] = __builtin_amdgcn_mfma_f32_16x16x32_bf16(ap0, bv0, o[dn], 0, 0, 0);
      o[dn] = __builtin_amdgcn_mfma_f32_16x16x32_bf16(ap1, bv1, o[dn], 0, 0, 0);
    }
    __syncthreads();
  }

  #pragma unroll
  for (int r = 0; r < 4; ++r) {
    const float inv = 1.0f / lrun[r];
    const int gq = tok0 + qt * 64 + wave * 16 + l4 * 4 + r;
    #pragma unroll
    for (int dn = 0; dn < 4; ++dn)
      hb[(size_t)gq * 5120 + d0 + dn * 16 + l15] = (bf16_t)(o[dn][r] * inv);
  }
}

// ---------------------------------------------------------------- final combine + tuple outputs
__global__ __launch_bounds__(256)
void final_kernel(const float* __restrict__ z, const float* __restrict__ x,
                  const int* __restrict__ em, const float* __restrict__ rp,
                  const float* __restrict__ alpha, float* __restrict__ out) {
  const int row = blockIdx.x, tid = threadIdx.x;
  const int e = em[row];
  const int dout = 2048 >> (3 - e);
  const float f = alpha[0] * rp[row * 4 + e] + 1.0f;
  const float* zr = z + (size_t)row * 2048;
  const float4 z0 = ((const float4*)zr)[tid];
  const float4 z1 = ((const float4*)(zr + 1024))[tid];
  const float4 xv = ((const float4*)(x + (size_t)row * 1024))[tid];
  const int c = tid * 4;
  float4 o;
  o.x = ((c + 0) < dout ? z0.x : 0.f) + xv.x + f * ((1024 + c + 0) < dout ? z1.x : 0.f);
  o.y = ((c + 1) < dout ? z0.y : 0.f) + xv.y + f * ((1024 + c + 1) < dout ? z1.y : 0.f);
  o.z = ((c + 2) < dout ? z0.z : 0.f) + xv.z + f * ((1024 + c + 2) < dout ? z1.z : 0.f);
  o.w = ((c + 3) < dout ? z0.w : 0.f) + xv.w + f * ((1024 + c + 3) < dout ? z1.w : 0.f);
  ((float4*)(out + (size_t)row * 1024))[tid] = o;
  float* out_em = out + 8388608;
  float* out_rp = out_em + 8192;
  if (tid == 0) out_em[row] = (float)e;
  if (tid < 4) out_rp[row * 4 + tid] = rp[row * 4 + tid];
}

// ---------------------------------------------------------------- launch
extern "C" void kernel_launch(void* const* d_in, const int* in_sizes, int n_in,
                              void* d_out, int out_size, void* d_ws, size_t ws_size,
                              hipStream_t stream) {
  const float* x = (const float*)d_in[0];
  const int* em = (const int*)d_in[1];
  const float* rp = (const float*)d_in[2];
  const float* w_exp = (const float*)d_in[3];
  const float* mlp_bias = (const float*)d_in[4];
  const float* w_con = (const float*)d_in[5];
  const float* c_bias = (const float*)d_in[6];
  const float* n1g = (const float*)d_in[7];
  const float* n1b = (const float*)d_in[8];
  const float* n2g = (const float*)d_in[9];
  const float* n2b = (const float*)d_in[10];
  const float* alpha = (const float*)d_in[11];

  char* ws = (char*)d_ws;
  bf16_t* Wexp = (bf16_t*)ws;
  bf16_t* xn   = (bf16_t*)(ws + 14680064);
  bf16_t* qb   = (bf16_t*)(ws + 14680064 + 16777216);
  bf16_t* kvb  = (bf16_t*)(ws + 14680064 + 33554432);
  bf16_t* Wcon = (bf16_t*)(ws + 14680064 + 67108864);
  bf16_t* hb   = (bf16_t*)(ws + 14680064 + 67108864 + 20971520);
  float*  z    = (float*)(ws + 14680064);  // alias over [xn|q|kv]

  cast_kernel<<<7168, 256, 0, stream>>>(w_exp, Wexp, 7340032);
  cast_kernel<<<10240, 256, 0, stream>>>(w_con, Wcon, 10485760);
  ln1_kernel<<<8192, 256, 0, stream>>>(x, n1g, n1b, em, xn);
  gemm8<0><<<32 * 28, 512, 0, stream>>>(xn, Wexp, 1024, mlp_bias, qb, kvb, hb, nullptr);
  ln2_kernel<<<8192, 256, 0, stream>>>(kvb, n2g, n2b);
  attn_kernel<<<dim3(16, 128), 256, 0, stream>>>(qb, kvb, hb);
  gemm8<1><<<32 * 8, 512, 0, stream>>>(hb, Wcon, 5120, c_bias, nullptr, nullptr, nullptr, z);
  final_kernel<<<8192, 256, 0, stream>>>(z, x, em, rp, alpha, (float*)d_out);
}

// Round 4
// 488.305 us; speedup vs baseline: 1.2939x; 1.2711x over previous
//
#include <hip/hip_runtime.h>
#include <hip/hip_bf16.h>
#include <math.h>

typedef __bf16 bf16_t;
typedef __attribute__((ext_vector_type(8))) __bf16 bf16x8;
typedef __attribute__((ext_vector_type(4))) __bf16 bf16x4;
typedef __attribute__((ext_vector_type(4))) float f32x4;

typedef __attribute__((address_space(1))) unsigned as1u;
typedef __attribute__((address_space(3))) unsigned as3u;

#define MAXT1 68
#define MAXJ2 1056

__device__ __forceinline__ void async_copy16(bf16_t* lds, const bf16_t* g) {
  __builtin_amdgcn_global_load_lds((as1u*)g, (as3u*)lds, 16, 0, 0);
}

__device__ __forceinline__ float gelu_exact(float t) {
  return 0.5f * t * (1.0f + erff(t * 0.70710678118654752f));
}

// ---------------------------------------------------------------- cast f32->bf16
__global__ __launch_bounds__(256)
void cast_kernel(const float* __restrict__ w, bf16_t* __restrict__ o, int n) {
  int i = (blockIdx.x * 256 + threadIdx.x) * 4;
  if (i < n) {
    float4 v = *(const float4*)(w + i);
    bf16x4 t;
    t[0] = (bf16_t)v.x; t[1] = (bf16_t)v.y; t[2] = (bf16_t)v.z; t[3] = (bf16_t)v.w;
    *(bf16x4*)(o + i) = t;
  }
}

// ---------------------------------------------------------------- expert sort + descriptors
// perm: gathered order (expert-grouped). t1: GEMM1 tile desc {e,row0,nval}x68.
// j2: GEMM2 job desc {e,row0,nval,bn}x1056. Sentinel e=-1. Output math is
// perm-order independent (no reduction crosses tokens), so atomic-order
// nondeterminism is harmless.
__global__ __launch_bounds__(1024)
void sort_kernel(const int* __restrict__ em, int* __restrict__ perm,
                 int* __restrict__ t1, int* __restrict__ j2) {
  __shared__ int cnt[4], cur[4], tb[5], jb[5];
  const int tid = threadIdx.x;
  const int wave = tid >> 6, lane = tid & 63;
  if (tid < 4) cnt[tid] = 0;
  __syncthreads();
  for (int c = wave; c < 128; c += 16) {
    int e = em[c * 64 + lane];
    unsigned long long m0 = __ballot(e == 0), m1 = __ballot(e == 1);
    unsigned long long m2 = __ballot(e == 2), m3 = __ballot(e == 3);
    if (lane == 0) {
      atomicAdd(&cnt[0], (int)__popcll(m0)); atomicAdd(&cnt[1], (int)__popcll(m1));
      atomicAdd(&cnt[2], (int)__popcll(m2)); atomicAdd(&cnt[3], (int)__popcll(m3));
    }
  }
  __syncthreads();
  if (tid == 0) {
    cur[0] = 0; cur[1] = cnt[0]; cur[2] = cnt[0] + cnt[1]; cur[3] = cnt[0] + cnt[1] + cnt[2];
    tb[0] = 0; jb[0] = 0;
    for (int e = 0; e < 4; ++e) {
      int nt = (cnt[e] + 127) >> 7;
      tb[e + 1] = tb[e] + nt;
      jb[e + 1] = jb[e] + nt * (2 << e);
    }
  }
  __syncthreads();
  for (int c = wave; c < 128; c += 16) {
    int i = c * 64 + lane;
    int e = em[i];
    unsigned long long m0 = __ballot(e == 0), m1 = __ballot(e == 1);
    unsigned long long m2 = __ballot(e == 2), m3 = __ballot(e == 3);
    unsigned long long me = e == 0 ? m0 : e == 1 ? m1 : e == 2 ? m2 : m3;
    int bl = 0;
    if (lane < 4) {
      unsigned long long ml = lane == 0 ? m0 : lane == 1 ? m1 : lane == 2 ? m2 : m3;
      bl = atomicAdd(&cur[lane], (int)__popcll(ml));
    }
    int base = __shfl(bl, e);
    unsigned long long lt = (1ull << lane) - 1ull;
    perm[base + (int)__popcll(me & lt)] = i;
  }
  // descriptors (all threads; depends only on cnt/tb/jb)
  int offp[5];
  offp[0] = 0;
  #pragma unroll
  for (int e = 0; e < 4; ++e) offp[e + 1] = offp[e] + cnt[e];
  for (int t = tid; t < MAXT1; t += 1024) {
    int e = -1, loc = 0;
    #pragma unroll
    for (int q = 0; q < 4; ++q) if (t >= tb[q] && t < tb[q + 1]) { e = q; loc = t - tb[q]; }
    if (e >= 0) {
      t1[t * 3] = e; t1[t * 3 + 1] = offp[e] + loc * 128;
      t1[t * 3 + 2] = min(128, cnt[e] - loc * 128);
    } else t1[t * 3] = -1;
  }
  for (int j = tid; j < MAXJ2; j += 1024) {
    int e = -1, loc = 0;
    #pragma unroll
    for (int q = 0; q < 4; ++q) if (j >= jb[q] && j < jb[q + 1]) { e = q; loc = j - jb[q]; }
    if (e >= 0) {
      int t = loc >> (1 + e), b = loc & ((2 << e) - 1);
      j2[j * 4] = e; j2[j * 4 + 1] = offp[e] + t * 128;
      j2[j * 4 + 2] = min(128, cnt[e] - t * 128); j2[j * 4 + 3] = b;
    } else j2[j * 4] = -1;
  }
}

// ---------------------------------------------------------------- LN1 + in-mask -> bf16
__global__ __launch_bounds__(256)
void ln1_kernel(const float* __restrict__ x, const float* __restrict__ gam,
                const float* __restrict__ bet, const int* __restrict__ em,
                bf16_t* __restrict__ xn) {
  const int row = blockIdx.x, tid = threadIdx.x;
  const float4 v = ((const float4*)(x + (size_t)row * 1024))[tid];
  float s = v.x + v.y + v.z + v.w;
  float sq = v.x * v.x + v.y * v.y + v.z * v.z + v.w * v.w;
  #pragma unroll
  for (int off = 1; off < 64; off <<= 1) { s += __shfl_xor(s, off); sq += __shfl_xor(sq, off); }
  __shared__ float red[8];
  const int wave = tid >> 6, lane = tid & 63;
  if (lane == 0) { red[wave] = s; red[4 + wave] = sq; }
  __syncthreads();
  s = red[0] + red[1] + red[2] + red[3];
  sq = red[4] + red[5] + red[6] + red[7];
  const float mean = s * (1.0f / 1024.0f);
  const float var = sq * (1.0f / 1024.0f) - mean * mean;
  const float rstd = rsqrtf(var + 1e-5f);
  const int din = 1024 >> (3 - em[row]);
  const float4 gv = ((const float4*)gam)[tid];
  const float4 bv = ((const float4*)bet)[tid];
  const int c0 = tid * 4;
  float vf[4] = {v.x, v.y, v.z, v.w};
  float gf[4] = {gv.x, gv.y, gv.z, gv.w};
  float bvf[4] = {bv.x, bv.y, bv.z, bv.w};
  bf16x4 o;
  #pragma unroll
  for (int i = 0; i < 4; ++i) {
    float t = (vf[i] - mean) * rstd * gf[i] + bvf[i];
    o[i] = (c0 + i < din) ? (bf16_t)t : (bf16_t)0.0f;
  }
  *(bf16x4*)(xn + (size_t)row * 1024 + c0) = o;
}

// ---------------------------------------------------------------- LN2 over k and v, in place (bf16)
__global__ __launch_bounds__(256)
void ln2_kernel(bf16_t* __restrict__ kv, const float* __restrict__ gam,
                const float* __restrict__ bet) {
  const int row = blockIdx.x, tid = threadIdx.x;
  bf16_t* base = kv + (size_t)row * 2048;
  bf16x4 kk = *(const bf16x4*)(base + tid * 4);
  bf16x4 vv = *(const bf16x4*)(base + 1024 + tid * 4);
  float kf[4], vf[4];
  float ks = 0, ksq = 0, vs = 0, vsq = 0;
  #pragma unroll
  for (int i = 0; i < 4; ++i) {
    kf[i] = (float)kk[i]; ks += kf[i]; ksq += kf[i] * kf[i];
    vf[i] = (float)vv[i]; vs += vf[i]; vsq += vf[i] * vf[i];
  }
  #pragma unroll
  for (int off = 1; off < 64; off <<= 1) {
    ks += __shfl_xor(ks, off); ksq += __shfl_xor(ksq, off);
    vs += __shfl_xor(vs, off); vsq += __shfl_xor(vsq, off);
  }
  __shared__ float red[16];
  const int wave = tid >> 6, lane = tid & 63;
  if (lane == 0) { red[wave] = ks; red[4 + wave] = ksq; red[8 + wave] = vs; red[12 + wave] = vsq; }
  __syncthreads();
  ks = red[0] + red[1] + red[2] + red[3];
  ksq = red[4] + red[5] + red[6] + red[7];
  vs = red[8] + red[9] + red[10] + red[11];
  vsq = red[12] + red[13] + red[14] + red[15];
  const float mk = ks * (1.f / 1024.f), mv = vs * (1.f / 1024.f);
  const float rk = rsqrtf(ksq * (1.f / 1024.f) - mk * mk + 1e-5f);
  const float rv = rsqrtf(vsq * (1.f / 1024.f) - mv * mv + 1e-5f);
  const float4 gv = ((const float4*)gam)[tid];
  const float4 bv = ((const float4*)bet)[tid];
  float gf[4] = {gv.x, gv.y, gv.z, gv.w}, bvf[4] = {bv.x, bv.y, bv.z, bv.w};
  bf16x4 ko, vo;
  #pragma unroll
  for (int i = 0; i < 4; ++i) {
    ko[i] = (bf16_t)((kf[i] - mk) * rk * gf[i] + bvf[i]);
    vo[i] = (bf16_t)((vf[i] - mv) * rv * gf[i] + bvf[i]);
  }
  *(bf16x4*)(base + tid * 4) = ko;
  *(bf16x4*)(base + 1024 + tid * 4) = vo;
}

// ---------------------------------------------------------------- expert-sparse bf16 GEMM
// Round-1 proven 128x128/BK=64 structure + gathered A rows (perm) + variable K-extent.
// EPI=0: expand (K_e = 128<<e of 1024), epilogue -> q(into hb[:, :1024]) | kv | gelu(mlp)->hb.
// EPI=1: contract (K=5120, only bn tiles with gc < d_out_e), epilogue -> z_attn f32 | z_mlp bf16.
template<int EPI>
__global__ __launch_bounds__(256)
void gemm_bt(const bf16_t* __restrict__ A, const bf16_t* __restrict__ W,
             const int* __restrict__ perm, const int* __restrict__ desc,
             const float* __restrict__ bias,
             bf16_t* __restrict__ hb, bf16_t* __restrict__ kvb,
             float* __restrict__ z_attn, bf16_t* __restrict__ z_mlp) {
  constexpr int K = (EPI == 0) ? 1024 : 5120;
  const int* d = desc + blockIdx.x * ((EPI == 0) ? 3 : 4);
  const int e = d[0];
  if (e < 0) return;
  const int nval = d[2];
  const int bn = (EPI == 0) ? blockIdx.y : d[3];
  const int nkt = (EPI == 0) ? (2 << e) : 80;

  __shared__ bf16_t As[128 * 64];
  __shared__ bf16_t Bs[128 * 64];
  __shared__ int prow[128];
  const int tid = threadIdx.x;
  if (tid < 128) prow[tid] = perm[d[1] + min(tid, nval - 1)];
  const int wave = tid >> 6, lane = tid & 63;
  const int l15 = lane & 15, l4 = lane >> 4;
  const int wm = wave >> 1, wn = wave & 1;

  f32x4 acc[4][4] = {};

  const int rbase = tid >> 3;
  const int ss = (tid & 7) ^ (rbase & 7);
  __syncthreads();
  const bf16_t* Ag[4];
  #pragma unroll
  for (int i = 0; i < 4; ++i) Ag[i] = A + (size_t)prow[i * 32 + rbase] * K + ss * 8;
  const bf16_t* Wg = W + (size_t)(bn * 128 + rbase) * K + ss * 8;

  for (int kt = 0; kt < nkt; ++kt) {
    #pragma unroll
    for (int i = 0; i < 4; ++i) {
      async_copy16(As + (i * 256 + wave * 64) * 8, Ag[i] + kt * 64);
      async_copy16(Bs + (i * 256 + wave * 64) * 8, Wg + (size_t)i * 32 * K + kt * 64);
    }
    __syncthreads();
    #pragma unroll
    for (int ks = 0; ks < 2; ++ks) {
      bf16x8 a[4], b[4];
      #pragma unroll
      for (int mi = 0; mi < 4; ++mi) {
        const int r = wm * 64 + mi * 16 + l15;
        const int slot = (ks * 4 + l4) ^ (r & 7);
        a[mi] = *(const bf16x8*)(As + r * 64 + slot * 8);
      }
      #pragma unroll
      for (int ni = 0; ni < 4; ++ni) {
        const int r = wn * 64 + ni * 16 + l15;
        const int slot = (ks * 4 + l4) ^ (r & 7);
        b[ni] = *(const bf16x8*)(Bs + r * 64 + slot * 8);
      }
      #pragma unroll
      for (int mi = 0; mi < 4; ++mi)
        #pragma unroll
        for (int ni = 0; ni < 4; ++ni)
          acc[mi][ni] = __builtin_amdgcn_mfma_f32_16x16x32_bf16(a[mi], b[ni], acc[mi][ni], 0, 0, 0);
    }
    __syncthreads();
  }

  // epilogue; C/D layout: row=(lane>>4)*4+reg, col=lane&15; scatter via prow
  #pragma unroll
  for (int mi = 0; mi < 4; ++mi) {
    #pragma unroll
    for (int ni = 0; ni < 4; ++ni) {
      const int gc = bn * 128 + wn * 64 + ni * 16 + l15;
      #pragma unroll
      for (int r = 0; r < 4; ++r) {
        const int gml = wm * 64 + mi * 16 + l4 * 4 + r;
        if (gml < nval) {
          const size_t token = (size_t)prow[gml];
          const float c = acc[mi][ni][r];
          if (EPI == 0) {
            if (gc < 1024) {
              hb[token * 5120 + gc] = (bf16_t)c;          // q parked in hb attn slot
            } else if (gc < 3072) {
              kvb[token * 2048 + (gc - 1024)] = (bf16_t)c;
            } else {
              const float t = c + bias[gc - 3072];
              hb[token * 5120 + 1024 + (gc - 3072)] = (bf16_t)gelu_exact(t);
            }
          } else {
            const float t = c + bias[gc];
            if (gc < 1024) z_attn[token * 1024 + gc] = t;
            else           z_mlp[token * 1024 + (gc - 1024)] = (bf16_t)t;
          }
        }
      }
    }
  }
}

// ---------------------------------------------------------------- flash attention
// q read from hb[:, head slice] (written by gemm1), output overwrites the same slice.
__global__ __launch_bounds__(256)
void attn_kernel(const bf16_t* __restrict__ kv, bf16_t* __restrict__ hb) {
  __shared__ bf16_t Kl[64 * 64];
  __shared__ bf16_t Vt[64 * 72];
  __shared__ bf16_t Pl[4][16 * 72];
  const int tid = threadIdx.x;
  const int wave = tid >> 6, lane = tid & 63;
  const int l15 = lane & 15, l4 = lane >> 4;
  const int qt = blockIdx.x, bh = blockIdx.y;
  const int bb = bh >> 4, head = bh & 15;
  const int tok0 = bb << 10;
  const int d0 = head << 6;

  const int qrow = tok0 + qt * 64 + wave * 16 + l15;
  const bf16x8 aq0 = *(const bf16x8*)(hb + (size_t)qrow * 5120 + d0 + l4 * 8);
  const bf16x8 aq1 = *(const bf16x8*)(hb + (size_t)qrow * 5120 + d0 + 32 + l4 * 8);

  f32x4 o[4] = {};
  float mrun[4] = {-1e30f, -1e30f, -1e30f, -1e30f};
  float lrun[4] = {0.f, 0.f, 0.f, 0.f};

  const int krb = tid >> 3;
  const int kss = (tid & 7) ^ (krb & 7);

  for (int kt = 0; kt < 16; ++kt) {
    const int krow0 = tok0 + kt * 64;
    #pragma unroll
    for (int i = 0; i < 2; ++i) {
      const int r = i * 32 + krb;
      async_copy16(Kl + (i * 256 + wave * 64) * 8,
                   kv + (size_t)(krow0 + r) * 2048 + d0 + kss * 8);
    }
    #pragma unroll
    for (int i = 0; i < 2; ++i) {
      const int key = i * 32 + (tid >> 3);
      const int dc = tid & 7;
      bf16x8 vvv = *(const bf16x8*)(kv + (size_t)(krow0 + key) * 2048 + 1024 + d0 + dc * 8);
      #pragma unroll
      for (int j = 0; j < 8; ++j) Vt[(dc * 8 + j) * 72 + key] = vvv[j];
    }
    __syncthreads();

    f32x4 s[4] = {};
    #pragma unroll
    for (int ks = 0; ks < 2; ++ks) {
      const bf16x8 aqk = ks ? aq1 : aq0;
      #pragma unroll
      for (int kc = 0; kc < 4; ++kc) {
        const int r = kc * 16 + l15;
        const int slot = (ks * 4 + l4) ^ (r & 7);
        bf16x8 bk = *(const bf16x8*)(Kl + r * 64 + slot * 8);
        s[kc] = __builtin_amdgcn_mfma_f32_16x16x32_bf16(aqk, bk, s[kc], 0, 0, 0);
      }
    }
    #pragma unroll
    for (int r = 0; r < 4; ++r) {
      float mx = -1e30f;
      #pragma unroll
      for (int kc = 0; kc < 4; ++kc) mx = fmaxf(mx, s[kc][r]);
      mx = fmaxf(mx, __shfl_xor(mx, 1));
      mx = fmaxf(mx, __shfl_xor(mx, 2));
      mx = fmaxf(mx, __shfl_xor(mx, 4));
      mx = fmaxf(mx, __shfl_xor(mx, 8));
      mx *= 0.125f;
      const float mnew = fmaxf(mrun[r], mx);
      const float corr = __expf(mrun[r] - mnew);
      float ps = 0.f;
      #pragma unroll
      for (int kc = 0; kc < 4; ++kc) {
        const float p = __expf(s[kc][r] * 0.125f - mnew);
        ps += p;
        Pl[wave][(l4 * 4 + r) * 72 + kc * 16 + l15] = (bf16_t)p;
      }
      ps += __shfl_xor(ps, 1); ps += __shfl_xor(ps, 2);
      ps += __shfl_xor(ps, 4); ps += __shfl_xor(ps, 8);
      lrun[r] = lrun[r] * corr + ps;
      mrun[r] = mnew;
      o[0][r] *= corr; o[1][r] *= corr; o[2][r] *= corr; o[3][r] *= corr;
    }
    const bf16x8 ap0 = *(const bf16x8*)(&Pl[wave][l15 * 72 + l4 * 8]);
    const bf16x8 ap1 = *(const bf16x8*)(&Pl[wave][l15 * 72 + 32 + l4 * 8]);
    #pragma unroll
    for (int dn = 0; dn < 4; ++dn) {
      const int r = dn * 16 + l15;
      bf16x8 bv0 = *(const bf16x8*)(Vt + r * 72 + l4 * 8);
      bf16x8 bv1 = *(const bf16x8*)(Vt + r * 72 + 32 + l4 * 8);
      o[dn] = __builtin_amdgcn_mfma_f32_16x16x32_bf16(ap0, bv0, o[dn], 0, 0, 0);
      o[dn] = __builtin_amdgcn_mfma_f32_16x16x32_bf16(ap1, bv1, o[dn], 0, 0, 0);
    }
    __syncthreads();
  }

  #pragma unroll
  for (int r = 0; r < 4; ++r) {
    const float inv = 1.0f / lrun[r];
    const int gq = tok0 + qt * 64 + wave * 16 + l4 * 4 + r;
    #pragma unroll
    for (int dn = 0; dn < 4; ++dn)
      hb[(size_t)gq * 5120 + d0 + dn * 16 + l15] = (bf16_t)(o[dn][r] * inv);
  }
}

// ---------------------------------------------------------------- final combine + tuple outputs
__global__ __launch_bounds__(256)
void final_kernel(const float* __restrict__ z_attn, const bf16_t* __restrict__ z_mlp,
                  const float* __restrict__ x, const int* __restrict__ em,
                  const float* __restrict__ rp, const float* __restrict__ alpha,
                  float* __restrict__ out) {
  const int row = blockIdx.x, tid = threadIdx.x;
  const int e = em[row];
  const int dout = 2048 >> (3 - e);
  const float f = alpha[0] * rp[row * 4 + e] + 1.0f;
  const float4 z0 = ((const float4*)(z_attn + (size_t)row * 1024))[tid];
  const bf16x4 z1 = ((const bf16x4*)(z_mlp + (size_t)row * 1024))[tid];
  const float4 xv = ((const float4*)(x + (size_t)row * 1024))[tid];
  const int c = tid * 4;
  float4 o;
  o.x = ((c + 0) < dout ? z0.x : 0.f) + xv.x + f * ((1024 + c + 0) < dout ? (float)z1[0] : 0.f);
  o.y = ((c + 1) < dout ? z0.y : 0.f) + xv.y + f * ((1024 + c + 1) < dout ? (float)z1[1] : 0.f);
  o.z = ((c + 2) < dout ? z0.z : 0.f) + xv.z + f * ((1024 + c + 2) < dout ? (float)z1[2] : 0.f);
  o.w = ((c + 3) < dout ? z0.w : 0.f) + xv.w + f * ((1024 + c + 3) < dout ? (float)z1[3] : 0.f);
  ((float4*)(out + (size_t)row * 1024))[tid] = o;
  float* out_em = out + 8388608;
  float* out_rp = out_em + 8192;
  if (tid == 0) out_em[row] = (float)e;
  if (tid < 4) out_rp[row * 4 + tid] = rp[row * 4 + tid];
}

// ---------------------------------------------------------------- launch
extern "C" void kernel_launch(void* const* d_in, const int* in_sizes, int n_in,
                              void* d_out, int out_size, void* d_ws, size_t ws_size,
                              hipStream_t stream) {
  const float* x = (const float*)d_in[0];
  const int* em = (const int*)d_in[1];
  const float* rp = (const float*)d_in[2];
  const float* w_exp = (const float*)d_in[3];
  const float* mlp_bias = (const float*)d_in[4];
  const float* w_con = (const float*)d_in[5];
  const float* c_bias = (const float*)d_in[6];
  const float* n1g = (const float*)d_in[7];
  const float* n1b = (const float*)d_in[8];
  const float* n2g = (const float*)d_in[9];
  const float* n2b = (const float*)d_in[10];
  const float* alpha = (const float*)d_in[11];

  char* ws = (char*)d_ws;
  // layout (bytes), total 186,646,528 (same envelope as rounds 1-3):
  //   0          Wexp bf16 (14,680,064)
  //   14,680,064 xn bf16 (16,777,216)          -> later z_mlp bf16 [8192x1024]
  //   31,457,280 perm int (32,768); t1 desc @ +32,768; j2 desc @ +34,816 (old q region, q now lives in hb)
  //   48,234,496 kv bf16 (33,554,432)          -> later z_attn f32 [8192x1024]
  //   81,788,928 Wcon bf16 (20,971,520)
  //  102,760,448 hb bf16 [8192x5120] (83,886,080): cols 0-1023 q->attn_out, 1024-5119 gelu(mlp)
  bf16_t* Wexp  = (bf16_t*)ws;
  bf16_t* xn    = (bf16_t*)(ws + 14680064);
  bf16_t* z_mlp = (bf16_t*)(ws + 14680064);
  int*    perm  = (int*)(ws + 31457280);
  int*    t1d   = (int*)(ws + 31457280 + 32768);
  int*    j2d   = (int*)(ws + 31457280 + 34816);
  bf16_t* kvb   = (bf16_t*)(ws + 48234496);
  float*  z_att = (float*)(ws + 48234496);
  bf16_t* Wcon  = (bf16_t*)(ws + 81788928);
  bf16_t* hb    = (bf16_t*)(ws + 102760448);

  sort_kernel<<<1, 1024, 0, stream>>>(em, perm, t1d, j2d);
  cast_kernel<<<7168, 256, 0, stream>>>(w_exp, Wexp, 7340032);
  cast_kernel<<<10240, 256, 0, stream>>>(w_con, Wcon, 10485760);
  ln1_kernel<<<8192, 256, 0, stream>>>(x, n1g, n1b, em, xn);
  gemm_bt<0><<<dim3(MAXT1, 56), 256, 0, stream>>>(xn, Wexp, perm, t1d, mlp_bias,
                                                  hb, kvb, nullptr, nullptr);
  ln2_kernel<<<8192, 256, 0, stream>>>(kvb, n2g, n2b);
  attn_kernel<<<dim3(16, 128), 256, 0, stream>>>(kvb, hb);
  gemm_bt<1><<<MAXJ2, 256, 0, stream>>>(hb, Wcon, perm, j2d, c_bias,
                                        nullptr, nullptr, z_att, z_mlp);
  final_kernel<<<8192, 256, 0, stream>>>(z_att, z_mlp, x, em, rp, alpha, (float*)d_out);
}

// Round 5
// 426.114 us; speedup vs baseline: 1.4828x; 1.1459x over previous
//
#include <hip/hip_runtime.h>
#include <hip/hip_bf16.h>
#include <math.h>

typedef __bf16 bf16_t;
typedef __attribute__((ext_vector_type(8))) __bf16 bf16x8;
typedef __attribute__((ext_vector_type(4))) __bf16 bf16x4;
typedef __attribute__((ext_vector_type(4))) float f32x4;
typedef __attribute__((ext_vector_type(4))) unsigned u32x4;

typedef __attribute__((address_space(1))) unsigned as1u;
typedef __attribute__((address_space(3))) unsigned as3u;

#define MAXT1 68
#define MAXJ2 1056

__device__ __forceinline__ void async_copy16(bf16_t* lds, const bf16_t* g) {
  __builtin_amdgcn_global_load_lds((as1u*)g, (as3u*)lds, 16, 0, 0);
}

__device__ __forceinline__ float gelu_exact(float t) {
  return 0.5f * t * (1.0f + erff(t * 0.70710678118654752f));
}

__device__ __forceinline__ unsigned pack_bf16(float a, float b) {
  unsigned short ha = __builtin_bit_cast(unsigned short, (bf16_t)a);
  unsigned short hb = __builtin_bit_cast(unsigned short, (bf16_t)b);
  return (unsigned)ha | ((unsigned)hb << 16);
}

// ---------------------------------------------------------------- cast f32->bf16
__global__ __launch_bounds__(256)
void cast_kernel(const float* __restrict__ w, bf16_t* __restrict__ o, int n) {
  int i = (blockIdx.x * 256 + threadIdx.x) * 4;
  if (i < n) {
    float4 v = *(const float4*)(w + i);
    bf16x4 t;
    t[0] = (bf16_t)v.x; t[1] = (bf16_t)v.y; t[2] = (bf16_t)v.z; t[3] = (bf16_t)v.w;
    *(bf16x4*)(o + i) = t;
  }
}

// ---------------------------------------------------------------- expert sort + descriptors
__global__ __launch_bounds__(1024)
void sort_kernel(const int* __restrict__ em, int* __restrict__ perm,
                 int* __restrict__ t1, int* __restrict__ j2) {
  __shared__ int cnt[4], cur[4], tb[5], jb[5];
  const int tid = threadIdx.x;
  const int wave = tid >> 6, lane = tid & 63;
  if (tid < 4) cnt[tid] = 0;
  __syncthreads();
  for (int c = wave; c < 128; c += 16) {
    int e = em[c * 64 + lane];
    unsigned long long m0 = __ballot(e == 0), m1 = __ballot(e == 1);
    unsigned long long m2 = __ballot(e == 2), m3 = __ballot(e == 3);
    if (lane == 0) {
      atomicAdd(&cnt[0], (int)__popcll(m0)); atomicAdd(&cnt[1], (int)__popcll(m1));
      atomicAdd(&cnt[2], (int)__popcll(m2)); atomicAdd(&cnt[3], (int)__popcll(m3));
    }
  }
  __syncthreads();
  if (tid == 0) {
    cur[0] = 0; cur[1] = cnt[0]; cur[2] = cnt[0] + cnt[1]; cur[3] = cnt[0] + cnt[1] + cnt[2];
    tb[0] = 0; jb[0] = 0;
    for (int e = 0; e < 4; ++e) {
      int nt = (cnt[e] + 127) >> 7;
      tb[e + 1] = tb[e] + nt;
      jb[e + 1] = jb[e] + nt * (2 << e);
    }
  }
  __syncthreads();
  for (int c = wave; c < 128; c += 16) {
    int i = c * 64 + lane;
    int e = em[i];
    unsigned long long m0 = __ballot(e == 0), m1 = __ballot(e == 1);
    unsigned long long m2 = __ballot(e == 2), m3 = __ballot(e == 3);
    unsigned long long me = e == 0 ? m0 : e == 1 ? m1 : e == 2 ? m2 : m3;
    int bl = 0;
    if (lane < 4) {
      unsigned long long ml = lane == 0 ? m0 : lane == 1 ? m1 : lane == 2 ? m2 : m3;
      bl = atomicAdd(&cur[lane], (int)__popcll(ml));
    }
    int base = __shfl(bl, e);
    unsigned long long lt = (1ull << lane) - 1ull;
    perm[base + (int)__popcll(me & lt)] = i;
  }
  int offp[5];
  offp[0] = 0;
  #pragma unroll
  for (int e = 0; e < 4; ++e) offp[e + 1] = offp[e] + cnt[e];
  for (int t = tid; t < MAXT1; t += 1024) {
    int e = -1, loc = 0;
    #pragma unroll
    for (int q = 0; q < 4; ++q) if (t >= tb[q] && t < tb[q + 1]) { e = q; loc = t - tb[q]; }
    if (e >= 0) {
      t1[t * 3] = e; t1[t * 3 + 1] = offp[e] + loc * 128;
      t1[t * 3 + 2] = min(128, cnt[e] - loc * 128);
    } else t1[t * 3] = -1;
  }
  for (int j = tid; j < MAXJ2; j += 1024) {
    int e = -1, loc = 0;
    #pragma unroll
    for (int q = 0; q < 4; ++q) if (j >= jb[q] && j < jb[q + 1]) { e = q; loc = j - jb[q]; }
    if (e >= 0) {
      int t = loc >> (1 + e), b = loc & ((2 << e) - 1);
      j2[j * 4] = e; j2[j * 4 + 1] = offp[e] + t * 128;
      j2[j * 4 + 2] = min(128, cnt[e] - t * 128); j2[j * 4 + 3] = b;
    } else j2[j * 4] = -1;
  }
}

// ---------------------------------------------------------------- LN1 + in-mask -> bf16
__global__ __launch_bounds__(256)
void ln1_kernel(const float* __restrict__ x, const float* __restrict__ gam,
                const float* __restrict__ bet, const int* __restrict__ em,
                bf16_t* __restrict__ xn) {
  const int row = blockIdx.x, tid = threadIdx.x;
  const float4 v = ((const float4*)(x + (size_t)row * 1024))[tid];
  float s = v.x + v.y + v.z + v.w;
  float sq = v.x * v.x + v.y * v.y + v.z * v.z + v.w * v.w;
  #pragma unroll
  for (int off = 1; off < 64; off <<= 1) { s += __shfl_xor(s, off); sq += __shfl_xor(sq, off); }
  __shared__ float red[8];
  const int wave = tid >> 6, lane = tid & 63;
  if (lane == 0) { red[wave] = s; red[4 + wave] = sq; }
  __syncthreads();
  s = red[0] + red[1] + red[2] + red[3];
  sq = red[4] + red[5] + red[6] + red[7];
  const float mean = s * (1.0f / 1024.0f);
  const float var = sq * (1.0f / 1024.0f) - mean * mean;
  const float rstd = rsqrtf(var + 1e-5f);
  const int din = 1024 >> (3 - em[row]);
  const float4 gv = ((const float4*)gam)[tid];
  const float4 bv = ((const float4*)bet)[tid];
  const int c0 = tid * 4;
  float vf[4] = {v.x, v.y, v.z, v.w};
  float gf[4] = {gv.x, gv.y, gv.z, gv.w};
  float bvf[4] = {bv.x, bv.y, bv.z, bv.w};
  bf16x4 o;
  #pragma unroll
  for (int i = 0; i < 4; ++i) {
    float t = (vf[i] - mean) * rstd * gf[i] + bvf[i];
    o[i] = (c0 + i < din) ? (bf16_t)t : (bf16_t)0.0f;
  }
  *(bf16x4*)(xn + (size_t)row * 1024 + c0) = o;
}

// ---------------------------------------------------------------- LN2 over k and v, in place (bf16)
__global__ __launch_bounds__(256)
void ln2_kernel(bf16_t* __restrict__ kv, const float* __restrict__ gam,
                const float* __restrict__ bet) {
  const int row = blockIdx.x, tid = threadIdx.x;
  bf16_t* base = kv + (size_t)row * 2048;
  bf16x4 kk = *(const bf16x4*)(base + tid * 4);
  bf16x4 vv = *(const bf16x4*)(base + 1024 + tid * 4);
  float kf[4], vf[4];
  float ks = 0, ksq = 0, vs = 0, vsq = 0;
  #pragma unroll
  for (int i = 0; i < 4; ++i) {
    kf[i] = (float)kk[i]; ks += kf[i]; ksq += kf[i] * kf[i];
    vf[i] = (float)vv[i]; vs += vf[i]; vsq += vf[i] * vf[i];
  }
  #pragma unroll
  for (int off = 1; off < 64; off <<= 1) {
    ks += __shfl_xor(ks, off); ksq += __shfl_xor(ksq, off);
    vs += __shfl_xor(vs, off); vsq += __shfl_xor(vsq, off);
  }
  __shared__ float red[16];
  const int wave = tid >> 6, lane = tid & 63;
  if (lane == 0) { red[wave] = ks; red[4 + wave] = ksq; red[8 + wave] = vs; red[12 + wave] = vsq; }
  __syncthreads();
  ks = red[0] + red[1] + red[2] + red[3];
  ksq = red[4] + red[5] + red[6] + red[7];
  vs = red[8] + red[9] + red[10] + red[11];
  vsq = red[12] + red[13] + red[14] + red[15];
  const float mk = ks * (1.f / 1024.f), mv = vs * (1.f / 1024.f);
  const float rk = rsqrtf(ksq * (1.f / 1024.f) - mk * mk + 1e-5f);
  const float rv = rsqrtf(vsq * (1.f / 1024.f) - mv * mv + 1e-5f);
  const float4 gv = ((const float4*)gam)[tid];
  const float4 bv = ((const float4*)bet)[tid];
  float gf[4] = {gv.x, gv.y, gv.z, gv.w}, bvf[4] = {bv.x, bv.y, bv.z, bv.w};
  bf16x4 ko, vo;
  #pragma unroll
  for (int i = 0; i < 4; ++i) {
    ko[i] = (bf16_t)((kf[i] - mk) * rk * gf[i] + bvf[i]);
    vo[i] = (bf16_t)((vf[i] - mv) * rv * gf[i] + bvf[i]);
  }
  *(bf16x4*)(base + tid * 4) = ko;
  *(bf16x4*)(base + 1024 + tid * 4) = vo;
}

// ---------------------------------------------------------------- V transpose: kv[tok][1024+d] -> vT[bh][d][tok]
__global__ __launch_bounds__(256)
void vt_kernel(const bf16_t* __restrict__ kv, bf16_t* __restrict__ vT) {
  __shared__ bf16_t t[64][80];
  const int tt = blockIdx.x, head = blockIdx.y;
  const int tid = threadIdx.x;
  const int r8 = tid >> 3, c8 = tid & 7;
  #pragma unroll
  for (int i = 0; i < 2; ++i) {
    const int tok = i * 32 + r8;
    bf16x8 v = *(const bf16x8*)(kv + (size_t)(tt * 64 + tok) * 2048 + 1024 + head * 64 + c8 * 8);
    #pragma unroll
    for (int j = 0; j < 8; ++j) t[c8 * 8 + j][tok] = v[j];
  }
  __syncthreads();
  const int bb = tt >> 4;
  const int tloc = (tt & 15) * 64;
  #pragma unroll
  for (int i = 0; i < 2; ++i) {
    const int d = i * 32 + r8;
    bf16x8 v = *(const bf16x8*)(&t[d][c8 * 8]);
    *(bf16x8*)(vT + (size_t)((bb * 16 + head) * 64 + d) * 1024 + tloc + c8 * 8) = v;
  }
}

// ---------------------------------------------------------------- expert-sparse bf16 GEMM (round-4 proven)
template<int EPI>
__global__ __launch_bounds__(256)
void gemm_bt(const bf16_t* __restrict__ A, const bf16_t* __restrict__ W,
             const int* __restrict__ perm, const int* __restrict__ desc,
             const float* __restrict__ bias,
             bf16_t* __restrict__ hb, bf16_t* __restrict__ kvb,
             float* __restrict__ z_attn, bf16_t* __restrict__ z_mlp) {
  constexpr int K = (EPI == 0) ? 1024 : 5120;
  const int* d = desc + blockIdx.x * ((EPI == 0) ? 3 : 4);
  const int e = d[0];
  if (e < 0) return;
  const int nval = d[2];
  const int bn = (EPI == 0) ? blockIdx.y : d[3];
  const int nkt = (EPI == 0) ? (2 << e) : 80;

  __shared__ bf16_t As[128 * 64];
  __shared__ bf16_t Bs[128 * 64];
  __shared__ int prow[128];
  const int tid = threadIdx.x;
  if (tid < 128) prow[tid] = perm[d[1] + min(tid, nval - 1)];
  const int wave = tid >> 6, lane = tid & 63;
  const int l15 = lane & 15, l4 = lane >> 4;
  const int wm = wave >> 1, wn = wave & 1;

  f32x4 acc[4][4] = {};

  const int rbase = tid >> 3;
  const int ss = (tid & 7) ^ (rbase & 7);
  __syncthreads();
  const bf16_t* Ag[4];
  #pragma unroll
  for (int i = 0; i < 4; ++i) Ag[i] = A + (size_t)prow[i * 32 + rbase] * K + ss * 8;
  const bf16_t* Wg = W + (size_t)(bn * 128 + rbase) * K + ss * 8;

  for (int kt = 0; kt < nkt; ++kt) {
    #pragma unroll
    for (int i = 0; i < 4; ++i) {
      async_copy16(As + (i * 256 + wave * 64) * 8, Ag[i] + kt * 64);
      async_copy16(Bs + (i * 256 + wave * 64) * 8, Wg + (size_t)i * 32 * K + kt * 64);
    }
    __syncthreads();
    #pragma unroll
    for (int ks = 0; ks < 2; ++ks) {
      bf16x8 a[4], b[4];
      #pragma unroll
      for (int mi = 0; mi < 4; ++mi) {
        const int r = wm * 64 + mi * 16 + l15;
        const int slot = (ks * 4 + l4) ^ (r & 7);
        a[mi] = *(const bf16x8*)(As + r * 64 + slot * 8);
      }
      #pragma unroll
      for (int ni = 0; ni < 4; ++ni) {
        const int r = wn * 64 + ni * 16 + l15;
        const int slot = (ks * 4 + l4) ^ (r & 7);
        b[ni] = *(const bf16x8*)(Bs + r * 64 + slot * 8);
      }
      #pragma unroll
      for (int mi = 0; mi < 4; ++mi)
        #pragma unroll
        for (int ni = 0; ni < 4; ++ni)
          acc[mi][ni] = __builtin_amdgcn_mfma_f32_16x16x32_bf16(a[mi], b[ni], acc[mi][ni], 0, 0, 0);
    }
    __syncthreads();
  }

  #pragma unroll
  for (int mi = 0; mi < 4; ++mi) {
    #pragma unroll
    for (int ni = 0; ni < 4; ++ni) {
      const int gc = bn * 128 + wn * 64 + ni * 16 + l15;
      #pragma unroll
      for (int r = 0; r < 4; ++r) {
        const int gml = wm * 64 + mi * 16 + l4 * 4 + r;
        if (gml < nval) {
          const size_t token = (size_t)prow[gml];
          const float c = acc[mi][ni][r];
          if (EPI == 0) {
            if (gc < 1024) {
              hb[token * 5120 + gc] = (bf16_t)c;
            } else if (gc < 3072) {
              kvb[token * 2048 + (gc - 1024)] = (bf16_t)c;
            } else {
              const float t = c + bias[gc - 3072];
              hb[token * 5120 + 1024 + (gc - 3072)] = (bf16_t)gelu_exact(t);
            }
          } else {
            const float t = c + bias[gc];
            if (gc < 1024) z_attn[token * 1024 + gc] = t;
            else           z_mlp[token * 1024 + (gc - 1024)] = (bf16_t)t;
          }
        }
      }
    }
  }
}

// ---------------------------------------------------------------- flash attention, swapped QK^T
// S^T = mfma(K, Q): lane (l4,l15) holds S[key=kc*16+l4*4+r][q=l15] -> softmax is
// in-lane + 2 shfl_xor. P repacked to bf16 and redistributed via 16 ds_bpermute
// (conflict-free) into PV A-frags. K and V^T staged via global_load_lds + XOR swizzle.
__global__ __launch_bounds__(256)
void attn_kernel(const bf16_t* __restrict__ kv, const bf16_t* __restrict__ vT,
                 bf16_t* __restrict__ hb) {
  __shared__ bf16_t Kl[64 * 64];
  __shared__ bf16_t Vl[64 * 64];
  const int tid = threadIdx.x;
  const int wave = tid >> 6, lane = tid & 63;
  const int l15 = lane & 15, l4 = lane >> 4;
  const int qt = blockIdx.x, bh = blockIdx.y;
  const int bb = bh >> 4;
  const int tok0 = bb << 10;
  const int d0 = (bh & 15) << 6;

  // Q as B-frag (row = q = l15 within this wave's 16-q tile)
  const int qrow = tok0 + qt * 64 + wave * 16 + l15;
  const bf16x8 bq0 = *(const bf16x8*)(hb + (size_t)qrow * 5120 + d0 + l4 * 8);
  const bf16x8 bq1 = *(const bf16x8*)(hb + (size_t)qrow * 5120 + d0 + 32 + l4 * 8);

  f32x4 o[4] = {};
  float mrun = -1e30f, lrun = 0.f;

  const int krb = tid >> 3;
  const int kss = (tid & 7) ^ (krb & 7);
  const int idx0 = ((2 * (l4 & 1) + 0) * 16 + l15) * 4;
  const int idx1 = ((2 * (l4 & 1) + 1) * 16 + l15) * 4;
  const bool hi = (l4 >> 1) != 0;

  for (int kt = 0; kt < 16; ++kt) {
    const int krow0 = tok0 + kt * 64;
    #pragma unroll
    for (int i = 0; i < 2; ++i) {
      async_copy16(Kl + (i * 256 + wave * 64) * 8,
                   kv + (size_t)(krow0 + i * 32 + krb) * 2048 + d0 + kss * 8);
      async_copy16(Vl + (i * 256 + wave * 64) * 8,
                   vT + (size_t)(bh * 64 + i * 32 + krb) * 1024 + kt * 64 + kss * 8);
    }
    __syncthreads();

    // S^T: s[kc] holds S[key = kc*16 + l4*4 + r][q = l15]
    f32x4 s[4] = {};
    #pragma unroll
    for (int ks = 0; ks < 2; ++ks) {
      const bf16x8 bq = ks ? bq1 : bq0;
      #pragma unroll
      for (int kc = 0; kc < 4; ++kc) {
        const int r = kc * 16 + l15;
        const int slot = (ks * 4 + l4) ^ (r & 7);
        bf16x8 ak = *(const bf16x8*)(Kl + r * 64 + slot * 8);
        s[kc] = __builtin_amdgcn_mfma_f32_16x16x32_bf16(ak, bq, s[kc], 0, 0, 0);
      }
    }

    // online softmax for q = l15 (16 keys in-lane, 4 l4-groups hold all 64)
    float mx = s[0][0];
    #pragma unroll
    for (int kc = 0; kc < 4; ++kc)
      #pragma unroll
      for (int r = 0; r < 4; ++r) mx = fmaxf(mx, s[kc][r]);
    mx = fmaxf(mx, __shfl_xor(mx, 16));
    mx = fmaxf(mx, __shfl_xor(mx, 32));
    mx *= 0.125f;
    const float mnew = fmaxf(mrun, mx);
    const float corr = __expf(mrun - mnew);
    float ps = 0.f;
    #pragma unroll
    for (int kc = 0; kc < 4; ++kc)
      #pragma unroll
      for (int r = 0; r < 4; ++r) {
        const float p = __expf(s[kc][r] * 0.125f - mnew);
        s[kc][r] = p;
        ps += p;
      }
    ps += __shfl_xor(ps, 16);
    ps += __shfl_xor(ps, 32);
    lrun = lrun * corr + ps;
    mrun = mnew;

    // pack P (consecutive-key pairs) and redistribute via bpermute
    unsigned pd[4][2], bp[4][2][2];
    #pragma unroll
    for (int kc = 0; kc < 4; ++kc) {
      pd[kc][0] = pack_bf16(s[kc][0], s[kc][1]);
      pd[kc][1] = pack_bf16(s[kc][2], s[kc][3]);
    }
    #pragma unroll
    for (int kc = 0; kc < 4; ++kc)
      #pragma unroll
      for (int rp = 0; rp < 2; ++rp) {
        bp[kc][rp][0] = (unsigned)__builtin_amdgcn_ds_bpermute(idx0, (int)pd[kc][rp]);
        bp[kc][rp][1] = (unsigned)__builtin_amdgcn_ds_bpermute(idx1, (int)pd[kc][rp]);
      }
    u32x4 w0, w1;
    w0[0] = hi ? bp[1][0][0] : bp[0][0][0];
    w0[1] = hi ? bp[1][1][0] : bp[0][1][0];
    w0[2] = hi ? bp[1][0][1] : bp[0][0][1];
    w0[3] = hi ? bp[1][1][1] : bp[0][1][1];
    w1[0] = hi ? bp[3][0][0] : bp[2][0][0];
    w1[1] = hi ? bp[3][1][0] : bp[2][1][0];
    w1[2] = hi ? bp[3][0][1] : bp[2][0][1];
    w1[3] = hi ? bp[3][1][1] : bp[2][1][1];
    const bf16x8 pa0 = __builtin_bit_cast(bf16x8, w0);
    const bf16x8 pa1 = __builtin_bit_cast(bf16x8, w1);

    // rescale O (row q = l4*4 + r)
    float cq[4];
    #pragma unroll
    for (int r = 0; r < 4; ++r) cq[r] = __shfl(corr, l4 * 4 + r);
    #pragma unroll
    for (int dn = 0; dn < 4; ++dn)
      #pragma unroll
      for (int r = 0; r < 4; ++r) o[dn][r] *= cq[r];

    // PV: O[q][d] += P[q][k] V^T[d][k]
    #pragma unroll
    for (int dn = 0; dn < 4; ++dn) {
      const int r = dn * 16 + l15;
      bf16x8 bv0 = *(const bf16x8*)(Vl + r * 64 + ((l4 ^ (r & 7)) * 8));
      bf16x8 bv1 = *(const bf16x8*)(Vl + r * 64 + (((4 + l4) ^ (r & 7)) * 8));
      o[dn] = __builtin_amdgcn_mfma_f32_16x16x32_bf16(pa0, bv0, o[dn], 0, 0, 0);
      o[dn] = __builtin_amdgcn_mfma_f32_16x16x32_bf16(pa1, bv1, o[dn], 0, 0, 0);
    }
    __syncthreads();
  }

  const float il = 1.0f / lrun;
  float linv[4];
  #pragma unroll
  for (int r = 0; r < 4; ++r) linv[r] = __shfl(il, l4 * 4 + r);
  #pragma unroll
  for (int r = 0; r < 4; ++r) {
    const int gq = tok0 + qt * 64 + wave * 16 + l4 * 4 + r;
    #pragma unroll
    for (int dn = 0; dn < 4; ++dn)
      hb[(size_t)gq * 5120 + d0 + dn * 16 + l15] = (bf16_t)(o[dn][r] * linv[r]);
  }
}

// ---------------------------------------------------------------- final combine + tuple outputs
__global__ __launch_bounds__(256)
void final_kernel(const float* __restrict__ z_attn, const bf16_t* __restrict__ z_mlp,
                  const float* __restrict__ x, const int* __restrict__ em,
                  const float* __restrict__ rp, const float* __restrict__ alpha,
                  float* __restrict__ out) {
  const int row = blockIdx.x, tid = threadIdx.x;
  const int e = em[row];
  const int dout = 2048 >> (3 - e);
  const float f = alpha[0] * rp[row * 4 + e] + 1.0f;
  const float4 z0 = ((const float4*)(z_attn + (size_t)row * 1024))[tid];
  const bf16x4 z1 = ((const bf16x4*)(z_mlp + (size_t)row * 1024))[tid];
  const float4 xv = ((const float4*)(x + (size_t)row * 1024))[tid];
  const int c = tid * 4;
  float4 o;
  o.x = ((c + 0) < dout ? z0.x : 0.f) + xv.x + f * ((1024 + c + 0) < dout ? (float)z1[0] : 0.f);
  o.y = ((c + 1) < dout ? z0.y : 0.f) + xv.y + f * ((1024 + c + 1) < dout ? (float)z1[1] : 0.f);
  o.z = ((c + 2) < dout ? z0.z : 0.f) + xv.z + f * ((1024 + c + 2) < dout ? (float)z1[2] : 0.f);
  o.w = ((c + 3) < dout ? z0.w : 0.f) + xv.w + f * ((1024 + c + 3) < dout ? (float)z1[3] : 0.f);
  ((float4*)(out + (size_t)row * 1024))[tid] = o;
  float* out_em = out + 8388608;
  float* out_rp = out_em + 8192;
  if (tid == 0) out_em[row] = (float)e;
  if (tid < 4) out_rp[row * 4 + tid] = rp[row * 4 + tid];
}

// ---------------------------------------------------------------- launch
extern "C" void kernel_launch(void* const* d_in, const int* in_sizes, int n_in,
                              void* d_out, int out_size, void* d_ws, size_t ws_size,
                              hipStream_t stream) {
  const float* x = (const float*)d_in[0];
  const int* em = (const int*)d_in[1];
  const float* rp = (const float*)d_in[2];
  const float* w_exp = (const float*)d_in[3];
  const float* mlp_bias = (const float*)d_in[4];
  const float* w_con = (const float*)d_in[5];
  const float* c_bias = (const float*)d_in[6];
  const float* n1g = (const float*)d_in[7];
  const float* n1b = (const float*)d_in[8];
  const float* n2g = (const float*)d_in[9];
  const float* n2b = (const float*)d_in[10];
  const float* alpha = (const float*)d_in[11];

  char* ws = (char*)d_ws;
  // layout (bytes), total 186,646,528:
  //   0          Wexp bf16 (14,680,064)
  //   14,680,064 xn bf16 (16,777,216)  -> vT bf16 [128 bh][64 d][1024 tok] (attn) -> z_mlp bf16 (gemm2)
  //   31,457,280 perm (32,768); t1 @ +32,768; j2 @ +34,816
  //   48,234,496 kv bf16 (33,554,432)  -> z_attn f32 [8192x1024] (gemm2)
  //   81,788,928 Wcon bf16 (20,971,520)
  //  102,760,448 hb bf16 [8192x5120]: cols 0-1023 q -> attn_out, 1024-5119 gelu(mlp)
  bf16_t* Wexp  = (bf16_t*)ws;
  bf16_t* xn    = (bf16_t*)(ws + 14680064);
  bf16_t* vT    = (bf16_t*)(ws + 14680064);
  bf16_t* z_mlp = (bf16_t*)(ws + 14680064);
  int*    perm  = (int*)(ws + 31457280);
  int*    t1d   = (int*)(ws + 31457280 + 32768);
  int*    j2d   = (int*)(ws + 31457280 + 34816);
  bf16_t* kvb   = (bf16_t*)(ws + 48234496);
  float*  z_att = (float*)(ws + 48234496);
  bf16_t* Wcon  = (bf16_t*)(ws + 81788928);
  bf16_t* hb    = (bf16_t*)(ws + 102760448);

  sort_kernel<<<1, 1024, 0, stream>>>(em, perm, t1d, j2d);
  cast_kernel<<<7168, 256, 0, stream>>>(w_exp, Wexp, 7340032);
  cast_kernel<<<10240, 256, 0, stream>>>(w_con, Wcon, 10485760);
  ln1_kernel<<<8192, 256, 0, stream>>>(x, n1g, n1b, em, xn);
  gemm_bt<0><<<dim3(MAXT1, 56), 256, 0, stream>>>(xn, Wexp, perm, t1d, mlp_bias,
                                                  hb, kvb, nullptr, nullptr);
  ln2_kernel<<<8192, 256, 0, stream>>>(kvb, n2g, n2b);
  vt_kernel<<<dim3(128, 16), 256, 0, stream>>>(kvb, vT);
  attn_kernel<<<dim3(16, 128), 256, 0, stream>>>(kvb, vT, hb);
  gemm_bt<1><<<MAXJ2, 256, 0, stream>>>(hb, Wcon, perm, j2d, c_bias,
                                        nullptr, nullptr, z_att, z_mlp);
  final_kernel<<<8192, 256, 0, stream>>>(z_att, z_mlp, x, em, rp, alpha, (float*)d_out);
}